// Round 4
// baseline (645.869 us; speedup 1.0000x reference)
//
#include <hip/hip_runtime.h>

#define LOG2E 1.44269504088896340736f

__device__ __forceinline__ float fast_tanh(float v) {
    return 1.0f - 2.0f * __builtin_amdgcn_rcpf(1.0f + __builtin_amdgcn_exp2f(2.0f * LOG2E * v));
}

// Four waves per batch-pair (one gate each):
//   role 0: gate i (rows   0.. 63) — owns batch 0's c/h recurrence
//   role 1: gate f (rows  64..127) — owns batch 1's c/h recurrence
//   role 2: gate g (rows 128..191)
//   role 3: gate o (rows 192..255)
// Each lane holds 64 W_hh floats (1 row) -> stays in true VGPRs (no AGPR split).
// Gate values + h exchanged through LDS, 2 barriers/step. Single h buffer is
// race-free: h reads are in [barrier2(t-1), barrier1(t)), writes in
// [barrier1(t), barrier2(t)).
__global__ void __launch_bounds__(256, 4)
lstm_fused(const float* __restrict__ x,      // [2048,512,1]
           const float* __restrict__ W_ih,   // [256,1]
           const float* __restrict__ W_hh,   // [256,64]
           const float* __restrict__ b_ih,   // [256]
           const float* __restrict__ b_hh,   // [256]
           const float* __restrict__ W_fc,   // [2,64]
           const float* __restrict__ b_fc,   // [2]
           float* __restrict__ out)          // [2048,2]
{
    constexpr int T = 512;
    __shared__ __align__(16) float hbuf[2][64];        // [batch][unit]
    __shared__ __align__(16) float exch[4][2][64];     // [gate][batch][unit]

    const int lane = threadIdx.x & 63;
    const int role = threadIdx.x >> 6;        // 0..3 == gate i,f,g,o
    const int b0   = blockIdx.x * 2;
    const int b1   = b0 + 1;

    // ---- W row for this (role, lane) ----
    const int row = role * 64 + lane;
    float w[64];
    {
        const float* Wr = W_hh + (long)row * 64;
        #pragma unroll
        for (int j = 0; j < 64; j += 4)
            *(float4*)&w[j] = *(const float4*)&Wr[j];
    }
    const float wx = W_ih[row];
    const float bs = b_ih[row] + b_hh[row];

    // Unified nonlinearity: n(v) = A + B * rcp(1 + exp2(k*v))
    //   sigmoid (i,f,o): k=-LOG2E,  A=0, B=1
    //   tanh    (g):     k=+2LOG2E, A=1, B=-2
    const float kR = (role == 2) ? (2.0f * LOG2E) : (-LOG2E);
    const float AR = (role == 2) ? 1.0f : 0.0f;
    const float BR = (role == 2) ? -2.0f : 1.0f;

    if (role == 0) {
        hbuf[0][lane] = 0.0f;
        hbuf[1][lane] = 0.0f;
    }
    __syncthreads();

    float c = 0.0f;     // cell state of own batch (only roles 0,1 use these)
    float hown = 0.0f;

    const float* x0p = x + (long)b0 * T;
    const float* x1p = x + (long)b1 * T;

    for (int tb = 0; tb < T; tb += 64) {
        // coalesced x chunk; per-step broadcast via readlane (uniform index)
        float xc0 = x0p[tb + lane];
        float xc1 = x1p[tb + lane];
        for (int tt = 0; tt < 64; ++tt) {
            float sx0 = __builtin_bit_cast(float,
                __builtin_amdgcn_readlane(__builtin_bit_cast(int, xc0), tt));
            float sx1 = __builtin_bit_cast(float,
                __builtin_amdgcn_readlane(__builtin_bit_cast(int, xc1), tt));

            float a0 = fmaf(sx0, wx, bs);
            float a1 = fmaf(sx1, wx, bs);

            // matvec over h (uniform-address broadcast reads from LDS)
            const float4* hA = (const float4*)&hbuf[0][0];
            const float4* hB = (const float4*)&hbuf[1][0];
            #pragma unroll
            for (int jc = 0; jc < 16; ++jc) {
                float4 hv0 = hA[jc];
                float4 hv1 = hB[jc];
                #pragma unroll
                for (int u = 0; u < 4; ++u) {
                    const int j = jc * 4 + u;
                    a0 = fmaf((&hv0.x)[u], w[j], a0);
                    a1 = fmaf((&hv1.x)[u], w[j], a1);
                }
            }

            // this wave's gate nonlinearity for both batches
            float n0 = fmaf(BR, __builtin_amdgcn_rcpf(1.0f + __builtin_amdgcn_exp2f(kR * a0)), AR);
            float n1 = fmaf(BR, __builtin_amdgcn_rcpf(1.0f + __builtin_amdgcn_exp2f(kR * a1)), AR);

            exch[role][0][lane] = n0;
            exch[role][1][lane] = n1;
            __syncthreads();

            if (role < 2) {   // owner of batch `role`
                const float ig = exch[0][role][lane];
                const float fg = exch[1][role][lane];
                const float gg = exch[2][role][lane];
                const float og = exch[3][role][lane];
                c    = fmaf(fg, c, ig * gg);
                hown = og * fast_tanh(c);
                hbuf[role][lane] = hown;
            }
            __syncthreads();
        }
    }

    // ---- epilogue: out[b_own,:] = h_own @ W_fc.T + b_fc (roles 0,1 only) ----
    if (role < 2) {
        const int   bown = b0 + role;
        const float wc0  = W_fc[lane];
        const float wc1  = W_fc[64 + lane];
        float p0 = hown * wc0;
        float p1 = hown * wc1;
        #pragma unroll
        for (int off = 32; off > 0; off >>= 1) {
            p0 += __shfl_down(p0, off);
            p1 += __shfl_down(p1, off);
        }
        if (lane == 0) {
            out[bown * 2 + 0] = p0 + b_fc[0];
            out[bown * 2 + 1] = p1 + b_fc[1];
        }
    }
}

extern "C" void kernel_launch(void* const* d_in, const int* in_sizes, int n_in,
                              void* d_out, int out_size, void* d_ws, size_t ws_size,
                              hipStream_t stream) {
    const float* x    = (const float*)d_in[0];
    const float* W_ih = (const float*)d_in[1];
    const float* W_hh = (const float*)d_in[2];
    const float* b_ih = (const float*)d_in[3];
    const float* b_hh = (const float*)d_in[4];
    const float* W_fc = (const float*)d_in[5];
    const float* b_fc = (const float*)d_in[6];
    float* out = (float*)d_out;

    dim3 grid(1024);   // one batch-pair per block, 4 gate-waves per block
    dim3 block(256);
    hipLaunchKernelGGL(lstm_fused, grid, block, 0, stream,
                       x, W_ih, W_hh, b_ih, b_hh, W_fc, b_fc, out);
}